// Round 1
// baseline (1999.546 us; speedup 1.0000x reference)
//
#include <hip/hip_runtime.h>

#define B 8
#define C 256
#define P1 2048
#define P2 4096
#define CQ 32

// ---------------------------------------------------------------------------
// Pointwise conv (1x1): y = W @ x + b over channel dim.
//   x: [B][C][P], W: [O][C], bias: [O]
//   TRANS=false: y[b][o][p]   (O = gridDim.y*32)
//   TRANS=true : y[b][p][o]   (only used for q, O == 32)
// grid: (P/256, O/32, B), block 256. W/bias indices are wave-uniform -> s_load.
// ---------------------------------------------------------------------------
template<int P, bool TRANS>
__global__ void conv1x1(const float* __restrict__ x, const float* __restrict__ W,
                        const float* __restrict__ bias, float* __restrict__ y) {
    const int t  = threadIdx.x;
    const int p  = blockIdx.x * 256 + t;
    const int o0 = blockIdx.y * 32;
    const int b  = blockIdx.z;
    const float* xb = x + (size_t)b * C * P;

    float acc[32];
#pragma unroll
    for (int o = 0; o < 32; ++o) acc[o] = 0.f;

    for (int c = 0; c < C; c += 4) {
        float xv0 = xb[(size_t)(c + 0) * P + p];
        float xv1 = xb[(size_t)(c + 1) * P + p];
        float xv2 = xb[(size_t)(c + 2) * P + p];
        float xv3 = xb[(size_t)(c + 3) * P + p];
#pragma unroll
        for (int o = 0; o < 32; ++o) {
            const float* wr = W + (size_t)(o0 + o) * C + c;
            acc[o] = fmaf(wr[0], xv0, acc[o]);
            acc[o] = fmaf(wr[1], xv1, acc[o]);
            acc[o] = fmaf(wr[2], xv2, acc[o]);
            acc[o] = fmaf(wr[3], xv3, acc[o]);
        }
    }

    if (TRANS) {
        float* yr = y + ((size_t)b * P + p) * 32;
#pragma unroll
        for (int o = 0; o < 32; o += 4) {
            float4 v;
            v.x = acc[o + 0] + bias[o0 + o + 0];
            v.y = acc[o + 1] + bias[o0 + o + 1];
            v.z = acc[o + 2] + bias[o0 + o + 2];
            v.w = acc[o + 3] + bias[o0 + o + 3];
            *(float4*)&yr[o] = v;
        }
    } else {
        const int Ot = gridDim.y * 32;
#pragma unroll
        for (int o = 0; o < 32; ++o)
            y[((size_t)b * Ot + (o0 + o)) * P + p] = acc[o] + bias[o0 + o];
    }
}

// ---------------------------------------------------------------------------
// Softmax row stats: for each (b,p): m = max_q energy(p,q), linv = 1/sum exp.
// energy(p,q) = sum_o qw[b][p][o] * kw[b][o][q]   (never materialized)
// grid: (P1/16, B), block 256. 16 rows/block; k column held in 32 VGPRs.
// ---------------------------------------------------------------------------
__global__ __launch_bounds__(256) void softmax_stats(
        const float* __restrict__ qw, const float* __restrict__ kw,
        float* __restrict__ mw, float* __restrict__ linvw) {
    const int t  = threadIdx.x;
    const int p0 = blockIdx.x * 16;
    const int b  = blockIdx.y;
    const float* qb = qw + ((size_t)b * P1 + p0) * CQ;
    const float* kb = kw + (size_t)b * CQ * P2;

    float m[16], l[16];
#pragma unroll
    for (int r = 0; r < 16; ++r) { m[r] = -1e30f; l[r] = 0.f; }

    for (int q = t; q < P2; q += 256) {
        float kc[CQ];
#pragma unroll
        for (int o = 0; o < CQ; ++o) kc[o] = kb[(size_t)o * P2 + q];
#pragma unroll
        for (int r = 0; r < 16; ++r) {
            const float* qr = qb + r * CQ;   // wave-uniform -> scalar loads
            float e = 0.f;
#pragma unroll
            for (int o = 0; o < CQ; ++o) e = fmaf(qr[o], kc[o], e);
            float mn = fmaxf(m[r], e);
            l[r] = l[r] * __expf(m[r] - mn) + __expf(e - mn);
            m[r] = mn;
        }
    }

    __shared__ float ms[16][257];
    __shared__ float ls[16][257];
#pragma unroll
    for (int r = 0; r < 16; ++r) { ms[r][t] = m[r]; ls[r][t] = l[r]; }
    __syncthreads();

    const int r = t >> 4, j = t & 15;
    float mm = -1e30f, ll = 0.f;
#pragma unroll
    for (int i = 0; i < 16; ++i) {
        float mv = ms[r][j * 16 + i], lv = ls[r][j * 16 + i];
        float mn = fmaxf(mm, mv);
        ll = ll * __expf(mm - mn) + lv * __expf(mv - mn);
        mm = mn;
    }
    __syncthreads();
    ms[r][j] = mm; ls[r][j] = ll;
    __syncthreads();

    if (t < 16) {
        float mm2 = -1e30f, ll2 = 0.f;
#pragma unroll
        for (int i = 0; i < 16; ++i) {
            float mv = ms[t][i], lv = ls[t][i];
            float mn = fmaxf(mm2, mv);
            ll2 = ll2 * __expf(mm2 - mn) + lv * __expf(mv - mn);
            mm2 = mn;
        }
        mw[(size_t)b * P1 + p0 + t]    = mm2;
        linvw[(size_t)b * P1 + p0 + t] = 1.0f / ll2;
    }
}

// ---------------------------------------------------------------------------
// out[b][c][q] = alpha * sum_p v[b][c][p] * att[b][p][q] + x2[b][c][q]
// att recomputed on the fly from q,k and the (m, 1/l) stats.
// grid: (P2/128, B*2), block 256. Tile: c_tile=128, q_tile=128, p_step=64.
// LDS: att tile 33.0 KB + v tile 33.8 KB = 66.8 KB -> 2 blocks/CU (512 blocks
// total = exactly 2/CU resident). Per-thread: 16c x 4q fp32 accumulators.
// ---------------------------------------------------------------------------
__global__ __launch_bounds__(256, 2) void attn_out(
        const float* __restrict__ qw, const float* __restrict__ kw,
        const float* __restrict__ vw, const float* __restrict__ mw,
        const float* __restrict__ linvw, const float* __restrict__ x2,
        const float* __restrict__ alpha_p, float* __restrict__ out) {
    __shared__ __attribute__((aligned(16))) float att_s[64][129];
    __shared__ __attribute__((aligned(16))) float vs[64][132];

    const int t  = threadIdx.x;
    const int q0 = blockIdx.x * 128;
    const int b  = blockIdx.y >> 1;
    const int c0 = (blockIdx.y & 1) * 128;

    const float* qb = qw + (size_t)b * P1 * CQ;
    const float* kb = kw + (size_t)b * CQ * P2;
    const float* vb = vw + ((size_t)b * C + c0) * P1;
    const float* mb = mw + (size_t)b * P1;
    const float* lb = linvw + (size_t)b * P1;

    // k column for this thread's att-build lane, held in regs all kernel long
    const int qa = q0 + (t & 127);
    const int g  = t >> 7;                  // wave-uniform pp-group (0 or 1)
    float kreg[CQ];
#pragma unroll
    for (int o = 0; o < CQ; ++o) kreg[o] = kb[(size_t)o * P2 + qa];

    const int tx = t & 31, ty = t >> 5;     // ty in 0..7
    const int pl = t & 63, cb = t >> 6;     // v-stage roles

    float acc[16][4];
#pragma unroll
    for (int i = 0; i < 16; ++i)
#pragma unroll
        for (int j = 0; j < 4; ++j) acc[i][j] = 0.f;

    for (int p0v = 0; p0v < P1; p0v += 64) {
        // ---- attention tile build: pp in [g*32, g*32+32), q = qa ----
#pragma unroll 2
        for (int i = 0; i < 32; ++i) {
            int pp = g * 32 + i;
            const float* qr = qb + (size_t)(p0v + pp) * CQ;   // wave-uniform
            float e = 0.f;
#pragma unroll
            for (int o = 0; o < CQ; ++o) e = fmaf(qr[o], kreg[o], e);
            float a = __expf(e - mb[p0v + pp]) * lb[p0v + pp];
            att_s[pp][t & 127] = a;
        }
        // ---- stage v tile (transpose to [p][c]) ----
#pragma unroll
        for (int j = 0; j < 32; ++j) {
            int c = cb + j * 4;
            vs[pl][c] = vb[(size_t)c * P1 + p0v + pl];
        }
        __syncthreads();
        // ---- main FMA: acc[c][q] += v[p][c] * att[p][q] ----
#pragma unroll 2
        for (int pp = 0; pp < 64; ++pp) {
            float a0 = att_s[pp][tx];
            float a1 = att_s[pp][tx + 32];
            float a2 = att_s[pp][tx + 64];
            float a3 = att_s[pp][tx + 96];
            float vvals[16];
            *(float4*)&vvals[0]  = *(const float4*)&vs[pp][ty * 16];
            *(float4*)&vvals[4]  = *(const float4*)&vs[pp][ty * 16 + 4];
            *(float4*)&vvals[8]  = *(const float4*)&vs[pp][ty * 16 + 8];
            *(float4*)&vvals[12] = *(const float4*)&vs[pp][ty * 16 + 12];
#pragma unroll
            for (int i = 0; i < 16; ++i) {
                acc[i][0] = fmaf(vvals[i], a0, acc[i][0]);
                acc[i][1] = fmaf(vvals[i], a1, acc[i][1]);
                acc[i][2] = fmaf(vvals[i], a2, acc[i][2]);
                acc[i][3] = fmaf(vvals[i], a3, acc[i][3]);
            }
        }
        __syncthreads();
    }

    const float alpha = alpha_p[0];
#pragma unroll
    for (int i = 0; i < 16; ++i) {
        int c = c0 + ty * 16 + i;
        const float* x2r = x2 + ((size_t)b * C + c) * P2 + q0;
        float* outr      = out + ((size_t)b * C + c) * P2 + q0;
#pragma unroll
        for (int j = 0; j < 4; ++j)
            outr[tx + 32 * j] = fmaf(alpha, acc[i][j], x2r[tx + 32 * j]);
    }
}

// ---------------------------------------------------------------------------
extern "C" void kernel_launch(void* const* d_in, const int* in_sizes, int n_in,
                              void* d_out, int out_size, void* d_ws, size_t ws_size,
                              hipStream_t stream) {
    const float* x1    = (const float*)d_in[0];
    const float* x2    = (const float*)d_in[1];
    const float* Wq    = (const float*)d_in[2];
    const float* bq    = (const float*)d_in[3];
    const float* Wk    = (const float*)d_in[4];
    const float* bk    = (const float*)d_in[5];
    const float* Wv    = (const float*)d_in[6];
    const float* bv    = (const float*)d_in[7];
    const float* alpha = (const float*)d_in[8];
    float* out = (float*)d_out;

    float* qw = (float*)d_ws;                    // [B][P1][CQ]  2.0 MB
    float* kw = qw + (size_t)B * P1 * CQ;        // [B][CQ][P2]  4.0 MB
    float* vw = kw + (size_t)B * CQ * P2;        // [B][C][P1]  16.8 MB
    float* mw = vw + (size_t)B * C * P1;         // [B][P1]
    float* lw = mw + (size_t)B * P1;             // [B][P1]  (stores 1/l)

    conv1x1<P1, true ><<<dim3(P1 / 256, 1, B), 256, 0, stream>>>(x1, Wq, bq, qw);
    conv1x1<P2, false><<<dim3(P2 / 256, 1, B), 256, 0, stream>>>(x2, Wk, bk, kw);
    conv1x1<P1, false><<<dim3(P1 / 256, 8, B), 256, 0, stream>>>(x1, Wv, bv, vw);
    softmax_stats<<<dim3(P1 / 16, B), 256, 0, stream>>>(qw, kw, mw, lw);
    attn_out<<<dim3(P2 / 128, B * 2), 256, 0, stream>>>(qw, kw, vw, mw, lw, x2, alpha, out);
}

// Round 2
// 494.854 us; speedup vs baseline: 4.0407x; 4.0407x over previous
//
#include <hip/hip_runtime.h>

#define B 8
#define C 256
#define P1 2048
#define P2 4096
#define CQ 32

typedef _Float16 h8 __attribute__((ext_vector_type(8)));
typedef _Float16 h4 __attribute__((ext_vector_type(4)));
typedef float f4 __attribute__((ext_vector_type(4)));

#define MFMA16(a, b, c) __builtin_amdgcn_mfma_f32_16x16x32_f16(a, b, c, 0, 0, 0)

// ---------------------------------------------------------------------------
// conv for q/k: y = W x + b, written TRANSPOSED as [b][p][32] f16 hi/lo.
// block 256 = 64 p-lanes x 4 c-groups; partial sums reduced through LDS.
// grid (B, P/64).
// ---------------------------------------------------------------------------
template<int P>
__global__ __launch_bounds__(256) void conv_qk(
        const float* __restrict__ x, const float* __restrict__ W,
        const float* __restrict__ bias,
        _Float16* __restrict__ yhi, _Float16* __restrict__ ylo) {
    __shared__ float red[4][64][33];   // +1 pad: writes hit distinct banks
    const int t  = threadIdx.x;
    const int b  = blockIdx.x;
    const int p0 = blockIdx.y * 64;
    const int pl = t & 63, cg = t >> 6;
    const float* xb = x + ((size_t)b * C + cg * 64) * P + p0 + pl;

    float acc[CQ];
#pragma unroll
    for (int o = 0; o < CQ; ++o) acc[o] = 0.f;
    for (int c = 0; c < 64; c += 4) {
        float x0 = xb[(size_t)(c + 0) * P];
        float x1 = xb[(size_t)(c + 1) * P];
        float x2v = xb[(size_t)(c + 2) * P];
        float x3 = xb[(size_t)(c + 3) * P];
#pragma unroll
        for (int o = 0; o < CQ; ++o) {
            const float* wr = W + o * C + cg * 64 + c;   // wave-uniform
            acc[o] = fmaf(wr[0], x0, acc[o]);
            acc[o] = fmaf(wr[1], x1, acc[o]);
            acc[o] = fmaf(wr[2], x2v, acc[o]);
            acc[o] = fmaf(wr[3], x3, acc[o]);
        }
    }
#pragma unroll
    for (int o = 0; o < CQ; ++o) red[cg][pl][o] = acc[o];
    __syncthreads();

    const int p = t & 63, og = (t >> 6) * 8;
    h8 hv, lv;
#pragma unroll
    for (int j = 0; j < 8; ++j) {
        float v = red[0][p][og + j] + red[1][p][og + j] +
                  red[2][p][og + j] + red[3][p][og + j] + bias[og + j];
        _Float16 h = (_Float16)v;
        hv[j] = h;
        lv[j] = (_Float16)(v - (float)h);
    }
    size_t row = ((size_t)b * P + p0 + p) * CQ + og;
    *(h8*)(yhi + row) = hv;
    *(h8*)(ylo + row) = lv;
}

// ---------------------------------------------------------------------------
// conv for v: [b][c][p1] f16 hi/lo. grid (B, P1/256, C/32), block 256.
// ---------------------------------------------------------------------------
__global__ __launch_bounds__(256) void conv_v(
        const float* __restrict__ x, const float* __restrict__ W,
        const float* __restrict__ bias,
        _Float16* __restrict__ vh, _Float16* __restrict__ vl) {
    const int t  = threadIdx.x;
    const int b  = blockIdx.x;
    const int p  = blockIdx.y * 256 + t;
    const int o0 = blockIdx.z * 32;
    const float* xb = x + (size_t)b * C * P1 + p;

    float acc[32];
#pragma unroll
    for (int o = 0; o < 32; ++o) acc[o] = 0.f;
    for (int c = 0; c < C; c += 4) {
        float x0 = xb[(size_t)(c + 0) * P1];
        float x1 = xb[(size_t)(c + 1) * P1];
        float x2v = xb[(size_t)(c + 2) * P1];
        float x3 = xb[(size_t)(c + 3) * P1];
#pragma unroll
        for (int o = 0; o < 32; ++o) {
            const float* wr = W + (size_t)(o0 + o) * C + c;
            acc[o] = fmaf(wr[0], x0, acc[o]);
            acc[o] = fmaf(wr[1], x1, acc[o]);
            acc[o] = fmaf(wr[2], x2v, acc[o]);
            acc[o] = fmaf(wr[3], x3, acc[o]);
        }
    }
#pragma unroll
    for (int o = 0; o < 32; ++o) {
        float v = acc[o] + bias[o0 + o];
        _Float16 h = (_Float16)v;
        size_t off = ((size_t)b * C + o0 + o) * P1 + p;
        vh[off] = h;
        vl[off] = (_Float16)(v - (float)h);
    }
}

// ---------------------------------------------------------------------------
// stats: linv[b][p] = 1 / sum_q exp(energy[p][q]); energy via 3-pass hi/lo
// f16 MFMA (no max subtraction: |e| <~ 45 << 88, exp fits fp32).
// block 512 = 8 waves: 4 p-tiles x 2 q-halves. grid (B, P1/64).
// ---------------------------------------------------------------------------
__global__ __launch_bounds__(512) void stats_l(
        const _Float16* __restrict__ qhi, const _Float16* __restrict__ qlo,
        const _Float16* __restrict__ khi, const _Float16* __restrict__ klo,
        float* __restrict__ linv) {
    __shared__ float lred[2][64];
    const int t = threadIdx.x;
    const int b = blockIdx.x;
    const int p0 = blockIdx.y * 64;
    const int w = t >> 6, lane = t & 63, ln = lane & 15, quad = lane >> 4;
    const int ptw = w & 3, qh_half = w >> 2;
    const int pbase = p0 + ptw * 16;

    h8 qh = *(const h8*)(qhi + ((size_t)b * P1 + pbase + ln) * CQ + quad * 8);
    h8 ql = *(const h8*)(qlo + ((size_t)b * P1 + pbase + ln) * CQ + quad * 8);

    f4 acc = {0.f, 0.f, 0.f, 0.f};
    const _Float16* khb = khi + (size_t)b * P2 * CQ;
    const _Float16* klb = klo + (size_t)b * P2 * CQ;

    for (int qc = qh_half * 2048; qc < qh_half * 2048 + 2048; qc += 32) {
#pragma unroll
        for (int tile = 0; tile < 2; ++tile) {
            int q = qc + tile * 16 + ln;
            h8 kh = *(const h8*)(khb + (size_t)q * CQ + quad * 8);
            h8 kl = *(const h8*)(klb + (size_t)q * CQ + quad * 8);
            f4 z = {0.f, 0.f, 0.f, 0.f};
            f4 e = MFMA16(ql, kh, z);
            e = MFMA16(qh, kl, e);
            e = MFMA16(qh, kh, e);
#pragma unroll
            for (int r = 0; r < 4; ++r) acc[r] += __expf(e[r]);
        }
    }
#pragma unroll
    for (int off = 1; off < 16; off <<= 1) {
#pragma unroll
        for (int r = 0; r < 4; ++r) acc[r] += __shfl_xor(acc[r], off);
    }
    if (ln == 0) *(f4*)&lred[qh_half][ptw * 16 + quad * 4] = acc;
    __syncthreads();
    if (t < 64)
        linv[(size_t)b * P1 + p0 + t] = 1.0f / (lred[0][t] + lred[1][t]);
}

// ---------------------------------------------------------------------------
// Fused attention-out GEMM, all-MFMA.
// Block tile 128c x 128q, K(=p) chunks of 64. 4 waves as (wc, wq) 2x2.
// Per chunk: energy (3-pass hi/lo MFMA) -> exp*linv -> f16 att to LDS
// (XOR-swizzled [q][p], conflict-free) -> out-GEMM (v hi/lo from global,
// per-lane b128 A-frags, fully coalesced). grid (16 bc, 32 q): id%8 keys on
// (b,c-half) so each XCD keeps a 2 MB v slice L2-resident.
// ---------------------------------------------------------------------------
__global__ __launch_bounds__(256, 2) void attn_gemm(
        const _Float16* __restrict__ qhi, const _Float16* __restrict__ qlo,
        const _Float16* __restrict__ khi, const _Float16* __restrict__ klo,
        const _Float16* __restrict__ vhi, const _Float16* __restrict__ vlo,
        const float* __restrict__ linv, const float* __restrict__ x2,
        const float* __restrict__ alpha_p, float* __restrict__ out) {
    __shared__ _Float16 att_s[128][64];   // 16 KB, XOR-swizzled on 8-half blocks

    const int t  = threadIdx.x;
    const int bc = blockIdx.x;
    const int b  = bc >> 1, c0 = (bc & 1) * 128;
    const int q0 = blockIdx.y * 128;
    const int w = t >> 6, wq = w & 1, wc = w >> 1;
    const int lane = t & 63, ln = lane & 15, quad = lane >> 4;
    const int sw = ln & 7;                // XOR swizzle key (= q row & 7)

    // resident k fragments for this wave's 64 q's
    h8 kh[4], kl[4];
#pragma unroll
    for (int nt = 0; nt < 4; ++nt) {
        int q = q0 + wq * 64 + nt * 16 + ln;
        kh[nt] = *(const h8*)(khi + ((size_t)b * P2 + q) * CQ + quad * 8);
        kl[nt] = *(const h8*)(klo + ((size_t)b * P2 + q) * CQ + quad * 8);
    }

    f4 acc[4][4];
#pragma unroll
    for (int mt = 0; mt < 4; ++mt)
#pragma unroll
        for (int nt = 0; nt < 4; ++nt) acc[mt][nt] = (f4){0.f, 0.f, 0.f, 0.f};

    // prefetch q frags for chunk 0
    h8 nqh[2], nql[2];
#pragma unroll
    for (int pt = 0; pt < 2; ++pt) {
        size_t r = ((size_t)b * P1 + wc * 32 + pt * 16 + ln) * CQ + quad * 8;
        nqh[pt] = *(const h8*)(qhi + r);
        nql[pt] = *(const h8*)(qlo + r);
    }

    for (int p0v = 0; p0v < P1; p0v += 64) {
        h8 cqh[2] = {nqh[0], nqh[1]};
        h8 cql[2] = {nql[0], nql[1]};
        if (p0v + 64 < P1) {
#pragma unroll
            for (int pt = 0; pt < 2; ++pt) {
                size_t r = ((size_t)b * P1 + p0v + 64 + wc * 32 + pt * 16 + ln) * CQ + quad * 8;
                nqh[pt] = *(const h8*)(qhi + r);
                nql[pt] = *(const h8*)(qlo + r);
            }
        }
        f4 lv[2];
#pragma unroll
        for (int pt = 0; pt < 2; ++pt)
            lv[pt] = *(const f4*)(linv + (size_t)b * P1 + p0v + wc * 32 + pt * 16 + quad * 4);

        // ---- energy + att build ----
#pragma unroll
        for (int pt = 0; pt < 2; ++pt) {
            int bcol = wc * 4 + pt * 2 + (quad >> 1);      // chunk-local p block
            int col  = ((bcol ^ sw) << 3) + (quad & 1) * 4;
#pragma unroll
            for (int nt = 0; nt < 4; ++nt) {
                f4 z = {0.f, 0.f, 0.f, 0.f};
                f4 e = MFMA16(cql[pt], kh[nt], z);
                e = MFMA16(cqh[pt], kl[nt], e);
                e = MFMA16(cqh[pt], kh[nt], e);
                h4 pk;
#pragma unroll
                for (int r = 0; r < 4; ++r)
                    pk[r] = (_Float16)(__expf(e[r]) * lv[pt][r]);
                *(h4*)&att_s[wq * 64 + nt * 16 + ln][col] = pk;
            }
        }
        __syncthreads();

        // ---- out GEMM over this p chunk ----
#pragma unroll
        for (int kk = 0; kk < 64; kk += 32) {
            h8 bf[4];
#pragma unroll
            for (int nt = 0; nt < 4; ++nt) {
                int bcol2 = (kk >> 3) + quad;
                bf[nt] = *(const h8*)&att_s[wq * 64 + nt * 16 + ln][(bcol2 ^ sw) << 3];
            }
            h8 av[4], al[4];
#pragma unroll
            for (int mt = 0; mt < 4; ++mt) {
                size_t off = ((size_t)b * C + c0 + wc * 64 + mt * 16 + ln) * P1
                           + p0v + kk + quad * 8;
                av[mt] = *(const h8*)(vhi + off);
                al[mt] = *(const h8*)(vlo + off);
            }
#pragma unroll
            for (int mt = 0; mt < 4; ++mt)
#pragma unroll
                for (int nt = 0; nt < 4; ++nt)
                    acc[mt][nt] = MFMA16(av[mt], bf[nt], acc[mt][nt]);
#pragma unroll
            for (int mt = 0; mt < 4; ++mt)
#pragma unroll
                for (int nt = 0; nt < 4; ++nt)
                    acc[mt][nt] = MFMA16(al[mt], bf[nt], acc[mt][nt]);
        }
        __syncthreads();
    }

    const float alpha = alpha_p[0];
#pragma unroll
    for (int mt = 0; mt < 4; ++mt) {
#pragma unroll
        for (int nt = 0; nt < 4; ++nt) {
            int q = q0 + wq * 64 + nt * 16 + ln;
#pragma unroll
            for (int r = 0; r < 4; ++r) {
                int c = c0 + wc * 64 + mt * 16 + quad * 4 + r;
                size_t o = ((size_t)b * C + c) * P2 + q;
                out[o] = fmaf(alpha, acc[mt][nt][r], x2[o]);
            }
        }
    }
}

// ---------------------------------------------------------------------------
extern "C" void kernel_launch(void* const* d_in, const int* in_sizes, int n_in,
                              void* d_out, int out_size, void* d_ws, size_t ws_size,
                              hipStream_t stream) {
    const float* x1    = (const float*)d_in[0];
    const float* x2    = (const float*)d_in[1];
    const float* Wq    = (const float*)d_in[2];
    const float* bq    = (const float*)d_in[3];
    const float* Wk    = (const float*)d_in[4];
    const float* bk    = (const float*)d_in[5];
    const float* Wv    = (const float*)d_in[6];
    const float* bv    = (const float*)d_in[7];
    const float* alpha = (const float*)d_in[8];
    float* out = (float*)d_out;

    _Float16* qh = (_Float16*)d_ws;                     // [B][P1][32]
    _Float16* ql = qh + (size_t)B * P1 * CQ;            // [B][P1][32]
    _Float16* kh = ql + (size_t)B * P1 * CQ;            // [B][P2][32] (k^T)
    _Float16* kl = kh + (size_t)B * P2 * CQ;            // [B][P2][32]
    _Float16* vh = kl + (size_t)B * P2 * CQ;            // [B][C][P1]
    _Float16* vl = vh + (size_t)B * C * P1;             // [B][C][P1]
    float*    li = (float*)(vl + (size_t)B * C * P1);   // [B][P1]

    conv_qk<P1><<<dim3(B, P1 / 64), 256, 0, stream>>>(x1, Wq, bq, qh, ql);
    conv_qk<P2><<<dim3(B, P2 / 64), 256, 0, stream>>>(x2, Wk, bk, kh, kl);
    conv_v<<<dim3(B, P1 / 256, C / 32), 256, 0, stream>>>(x1, Wv, bv, vh, vl);
    stats_l<<<dim3(B, P1 / 64), 512, 0, stream>>>(qh, ql, kh, kl, li);
    attn_gemm<<<dim3(16, 32), 256, 0, stream>>>(qh, ql, kh, kl, vh, vl, li, x2, alpha, out);
}

// Round 3
// 279.258 us; speedup vs baseline: 7.1602x; 1.7720x over previous
//
#include <hip/hip_runtime.h>

#define B 8
#define C 256
#define P1 2048
#define P2 4096
#define CQ 32

typedef _Float16 h8 __attribute__((ext_vector_type(8)));
typedef _Float16 h4 __attribute__((ext_vector_type(4)));
typedef float f4 __attribute__((ext_vector_type(4)));

#define MFMA16(a, b, c) __builtin_amdgcn_mfma_f32_16x16x32_f16(a, b, c, 0, 0, 0)

// ---------------------------------------------------------------------------
// Convert weights to f16 hi/lo once. grid 32 x 256.
// ---------------------------------------------------------------------------
__global__ void prep_w(const float* __restrict__ Wq, const float* __restrict__ Wk,
                       const float* __restrict__ Wv,
                       _Float16* __restrict__ Wqh, _Float16* __restrict__ Wql,
                       _Float16* __restrict__ Wkh, _Float16* __restrict__ Wkl,
                       _Float16* __restrict__ Wvh) {
    const int i = blockIdx.x * 256 + threadIdx.x;
    if (i < CQ * C) {
        float a = Wq[i]; _Float16 h = (_Float16)a;
        Wqh[i] = h; Wql[i] = (_Float16)(a - (float)h);
        float b2 = Wk[i]; _Float16 h2 = (_Float16)b2;
        Wkh[i] = h2; Wkl[i] = (_Float16)(b2 - (float)h2);
    }
    for (int j = i; j < C * C; j += 32 * 256)
        Wvh[j] = (_Float16)Wv[j];
}

// ---------------------------------------------------------------------------
// prep1: from x1 compute q (hi/lo, [b][p][32], 3-pass) and v (hi, [b][c][p],
// 2-pass) via MFMA. x1 tile staged fp32 in LDS [32p][257c] (pad-1, conflict-
// free b32); hi/lo B-frags built in registers. grid (B, P1/32), block 256.
// ---------------------------------------------------------------------------
__global__ __launch_bounds__(256) void prep1(
        const float* __restrict__ x1,
        const _Float16* __restrict__ Wqh, const _Float16* __restrict__ Wql,
        const _Float16* __restrict__ Wvh,
        const float* __restrict__ bq, const float* __restrict__ bv,
        _Float16* __restrict__ qhw, _Float16* __restrict__ qlw,
        _Float16* __restrict__ vhw) {
    __shared__ float xs[32][257];
    const int t  = threadIdx.x;
    const int b  = blockIdx.x;
    const int p0 = blockIdx.y * 32;
    const float* xb = x1 + (size_t)b * C * P1;

    {   // stage tile [256c][32p] -> LDS [p][c]
        const int pl = t & 31, cg = t >> 5;
#pragma unroll 8
        for (int i = 0; i < 32; ++i) {
            int c = cg * 32 + i;
            xs[pl][c] = xb[(size_t)c * P1 + p0 + pl];
        }
    }
    __syncthreads();

    const int w = t >> 6, lane = t & 63, ln = lane & 15, quad = lane >> 4;
    const int nh = w & 1, ch = w >> 1;
    const int prow = nh * 16 + ln;

    f4 accv[8];
#pragma unroll
    for (int mt = 0; mt < 8; ++mt) accv[mt] = (f4){0.f, 0.f, 0.f, 0.f};
    f4 accq = {0.f, 0.f, 0.f, 0.f};

    for (int ks = 0; ks < 8; ++ks) {
        const int c0 = ks * 32 + quad * 8;
        h8 bh, bl;
#pragma unroll
        for (int j = 0; j < 8; ++j) {
            float xv = xs[prow][c0 + j];
            _Float16 hh = (_Float16)xv;
            bh[j] = hh; bl[j] = (_Float16)(xv - (float)hh);
        }
#pragma unroll
        for (int mt = 0; mt < 8; ++mt) {
            h8 a = *(const h8*)&Wvh[(size_t)((ch * 8 + mt) * 16 + ln) * C + c0];
            accv[mt] = MFMA16(a, bh, accv[mt]);
            accv[mt] = MFMA16(a, bl, accv[mt]);
        }
        {
            h8 aqh = *(const h8*)&Wqh[(size_t)(ch * 16 + ln) * C + c0];
            h8 aql = *(const h8*)&Wql[(size_t)(ch * 16 + ln) * C + c0];
            accq = MFMA16(aql, bh, accq);
            accq = MFMA16(aqh, bl, accq);
            accq = MFMA16(aqh, bh, accq);
        }
    }

    // v epilogue: C-frag col=p(ln), row=c(quad*4+r)
#pragma unroll
    for (int mt = 0; mt < 8; ++mt) {
        int cb = (ch * 8 + mt) * 16 + quad * 4;
        f4 bvv = *(const f4*)&bv[cb];
#pragma unroll
        for (int r = 0; r < 4; ++r)
            vhw[((size_t)b * C + cb + r) * P1 + p0 + prow] =
                (_Float16)(accv[mt][r] + bvv[r]);
    }
    // q epilogue: hi/lo pack
    {
        int ob = ch * 16 + quad * 4;
        f4 bqv = *(const f4*)&bq[ob];
        h4 hv, lv;
#pragma unroll
        for (int r = 0; r < 4; ++r) {
            float val = accq[r] + bqv[r];
            _Float16 hh = (_Float16)val;
            hv[r] = hh; lv[r] = (_Float16)(val - (float)hh);
        }
        size_t row = ((size_t)b * P1 + p0 + prow) * CQ + ob;
        *(h4*)(qhw + row) = hv;
        *(h4*)(qlw + row) = lv;
    }
}

// ---------------------------------------------------------------------------
// prep2: k (hi/lo, [b][q][32], 3-pass) from x2. grid (B, P2/32), block 256.
// ---------------------------------------------------------------------------
__global__ __launch_bounds__(256) void prep2(
        const float* __restrict__ x2,
        const _Float16* __restrict__ Wkh, const _Float16* __restrict__ Wkl,
        const float* __restrict__ bk,
        _Float16* __restrict__ khw, _Float16* __restrict__ klw) {
    __shared__ float xs[32][257];
    const int t  = threadIdx.x;
    const int b  = blockIdx.x;
    const int p0 = blockIdx.y * 32;
    const float* xb = x2 + (size_t)b * C * P2;
    {
        const int pl = t & 31, cg = t >> 5;
#pragma unroll 8
        for (int i = 0; i < 32; ++i) {
            int c = cg * 32 + i;
            xs[pl][c] = xb[(size_t)c * P2 + p0 + pl];
        }
    }
    __syncthreads();

    const int w = t >> 6, lane = t & 63, ln = lane & 15, quad = lane >> 4;
    const int nh = w & 1, mh = w >> 1;
    const int prow = nh * 16 + ln;

    f4 accq = {0.f, 0.f, 0.f, 0.f};
    for (int ks = 0; ks < 8; ++ks) {
        const int c0 = ks * 32 + quad * 8;
        h8 bh, bl;
#pragma unroll
        for (int j = 0; j < 8; ++j) {
            float xv = xs[prow][c0 + j];
            _Float16 hh = (_Float16)xv;
            bh[j] = hh; bl[j] = (_Float16)(xv - (float)hh);
        }
        h8 akh = *(const h8*)&Wkh[(size_t)(mh * 16 + ln) * C + c0];
        h8 akl = *(const h8*)&Wkl[(size_t)(mh * 16 + ln) * C + c0];
        accq = MFMA16(akl, bh, accq);
        accq = MFMA16(akh, bl, accq);
        accq = MFMA16(akh, bh, accq);
    }
    {
        int ob = mh * 16 + quad * 4;
        f4 bkv = *(const f4*)&bk[ob];
        h4 hv, lv;
#pragma unroll
        for (int r = 0; r < 4; ++r) {
            float val = accq[r] + bkv[r];
            _Float16 hh = (_Float16)val;
            hv[r] = hh; lv[r] = (_Float16)(val - (float)hh);
        }
        size_t row = ((size_t)b * P2 + p0 + prow) * CQ + ob;
        *(h4*)(khw + row) = hv;
        *(h4*)(klw + row) = lv;
    }
}

// ---------------------------------------------------------------------------
// stats: linv[b][p] = 1 / sum_q exp(energy[p][q]); 3-pass hi/lo f16 MFMA.
// (no max subtraction: |e| <~ 40 << 88, exp and sum fit fp32)
// block 512 = 8 waves: 4 p-tiles x 2 q-halves. grid (B, P1/64).
// ---------------------------------------------------------------------------
__global__ __launch_bounds__(512) void stats_l(
        const _Float16* __restrict__ qhi, const _Float16* __restrict__ qlo,
        const _Float16* __restrict__ khi, const _Float16* __restrict__ klo,
        float* __restrict__ linv) {
    __shared__ float lred[2][64];
    const int t = threadIdx.x;
    const int b = blockIdx.x;
    const int p0 = blockIdx.y * 64;
    const int w = t >> 6, lane = t & 63, ln = lane & 15, quad = lane >> 4;
    const int ptw = w & 3, qh_half = w >> 2;
    const int pbase = p0 + ptw * 16;

    h8 qh = *(const h8*)(qhi + ((size_t)b * P1 + pbase + ln) * CQ + quad * 8);
    h8 ql = *(const h8*)(qlo + ((size_t)b * P1 + pbase + ln) * CQ + quad * 8);

    f4 acc = {0.f, 0.f, 0.f, 0.f};
    const _Float16* khb = khi + (size_t)b * P2 * CQ;
    const _Float16* klb = klo + (size_t)b * P2 * CQ;

    for (int qc = qh_half * 2048; qc < qh_half * 2048 + 2048; qc += 32) {
#pragma unroll
        for (int tile = 0; tile < 2; ++tile) {
            int q = qc + tile * 16 + ln;
            h8 kh = *(const h8*)(khb + (size_t)q * CQ + quad * 8);
            h8 kl = *(const h8*)(klb + (size_t)q * CQ + quad * 8);
            f4 z = {0.f, 0.f, 0.f, 0.f};
            f4 e = MFMA16(ql, kh, z);
            e = MFMA16(qh, kl, e);
            e = MFMA16(qh, kh, e);
#pragma unroll
            for (int r = 0; r < 4; ++r) acc[r] += __expf(e[r]);
        }
    }
#pragma unroll
    for (int off = 1; off < 16; off <<= 1) {
#pragma unroll
        for (int r = 0; r < 4; ++r) acc[r] += __shfl_xor(acc[r], off);
    }
    if (ln == 0) *(f4*)&lred[qh_half][ptw * 16 + quad * 4] = acc;
    __syncthreads();
    if (t < 64)
        linv[(size_t)b * P1 + p0 + t] = 1.0f / (lred[0][t] + lred[1][t]);
}

// ---------------------------------------------------------------------------
// Fused attention-out GEMM. Tile: FULL C=256 x q-64, p chunks of 64.
// 4 waves = c-quarters; energy split by wave over p-tiles (no c-duplication).
// Double-buffered att LDS -> ONE barrier per chunk. v hi-only A-frags from
// global (L2-resident via b=id%8 XCD pinning). grid 512 = (8b x 64qt).
// ---------------------------------------------------------------------------
__global__ __launch_bounds__(256, 2) void attn_gemm(
        const _Float16* __restrict__ qhi, const _Float16* __restrict__ qlo,
        const _Float16* __restrict__ khi, const _Float16* __restrict__ klo,
        const _Float16* __restrict__ vhi, const float* __restrict__ linv,
        const float* __restrict__ x2, const float* __restrict__ alpha_p,
        float* __restrict__ out) {
    __shared__ _Float16 att_s[2][64][64];   // 16 KB, XOR-swizzled 8-granules

    const int t  = threadIdx.x;
    const int b  = blockIdx.x & 7;          // XCD-pinned: L2 keeps v[b] slice
    const int q0 = (blockIdx.x >> 3) * 64;
    const int wc = t >> 6;                  // c-quarter
    const int lane = t & 63, ln = lane & 15, quad = lane >> 4;
    const int sw = ln & 7;

    // resident k fragments for this block's 64 q's
    h8 kh[4], kl[4];
#pragma unroll
    for (int nt = 0; nt < 4; ++nt) {
        int q = q0 + nt * 16 + ln;
        kh[nt] = *(const h8*)(khi + ((size_t)b * P2 + q) * CQ + quad * 8);
        kl[nt] = *(const h8*)(klo + ((size_t)b * P2 + q) * CQ + quad * 8);
    }

    f4 acc[4][4];
#pragma unroll
    for (int mt = 0; mt < 4; ++mt)
#pragma unroll
        for (int nt = 0; nt < 4; ++nt) acc[mt][nt] = (f4){0.f, 0.f, 0.f, 0.f};

    // prefetch q frags for chunk 0 (this wave's p-tile = wc)
    h8 nqh, nql;
    {
        size_t r = ((size_t)b * P1 + wc * 16 + ln) * CQ + quad * 8;
        nqh = *(const h8*)(qhi + r);
        nql = *(const h8*)(qlo + r);
    }

    const int wbcol = wc * 2 + (quad >> 1);
    const int wcol  = ((wbcol ^ sw) << 3) + (quad & 1) * 4;

    for (int pc = 0; pc < P1 / 64; ++pc) {
        const int p0v = pc * 64;
        h8 cqh = nqh, cql = nql;
        if (pc + 1 < P1 / 64) {
            size_t r = ((size_t)b * P1 + p0v + 64 + wc * 16 + ln) * CQ + quad * 8;
            nqh = *(const h8*)(qhi + r);
            nql = *(const h8*)(qlo + r);
        }
        f4 lv = *(const f4*)(linv + (size_t)b * P1 + p0v + wc * 16 + quad * 4);

        _Float16* abuf = &att_s[pc & 1][0][0];
        // ---- energy + att for p-tile wc ----
#pragma unroll
        for (int nt = 0; nt < 4; ++nt) {
            f4 z = {0.f, 0.f, 0.f, 0.f};
            f4 e = MFMA16(cql, kh[nt], z);
            e = MFMA16(cqh, kl[nt], e);
            e = MFMA16(cqh, kh[nt], e);
            h4 pk;
#pragma unroll
            for (int r = 0; r < 4; ++r)
                pk[r] = (_Float16)(__expf(e[r]) * lv[r]);
            *(h4*)&abuf[(nt * 16 + ln) * 64 + wcol] = pk;
        }
        __syncthreads();

        // ---- out GEMM over this p chunk (hi-only v) ----
#pragma unroll
        for (int kk = 0; kk < 64; kk += 32) {
            h8 bf[4];
#pragma unroll
            for (int nt = 0; nt < 4; ++nt) {
                int bcol2 = (kk >> 3) + quad;
                bf[nt] = *(const h8*)&abuf[(nt * 16 + ln) * 64 + ((bcol2 ^ sw) << 3)];
            }
            h8 av[4];
#pragma unroll
            for (int mt = 0; mt < 4; ++mt) {
                size_t off = ((size_t)b * C + wc * 64 + mt * 16 + ln) * P1
                           + p0v + kk + quad * 8;
                av[mt] = *(const h8*)(vhi + off);
            }
#pragma unroll
            for (int mt = 0; mt < 4; ++mt)
#pragma unroll
                for (int nt = 0; nt < 4; ++nt)
                    acc[mt][nt] = MFMA16(av[mt], bf[nt], acc[mt][nt]);
        }
        // no second barrier: next chunk writes the other buffer; the next
        // iteration's barrier orders its writes against this chunk's reads
    }

    const float alpha = alpha_p[0];
#pragma unroll
    for (int mt = 0; mt < 4; ++mt) {
#pragma unroll
        for (int nt = 0; nt < 4; ++nt) {
            int q = q0 + nt * 16 + ln;
#pragma unroll
            for (int r = 0; r < 4; ++r) {
                int c = wc * 64 + mt * 16 + quad * 4 + r;
                size_t o = ((size_t)b * C + c) * P2 + q;
                out[o] = fmaf(alpha, acc[mt][nt][r], x2[o]);
            }
        }
    }
}

// ---------------------------------------------------------------------------
extern "C" void kernel_launch(void* const* d_in, const int* in_sizes, int n_in,
                              void* d_out, int out_size, void* d_ws, size_t ws_size,
                              hipStream_t stream) {
    const float* x1    = (const float*)d_in[0];
    const float* x2    = (const float*)d_in[1];
    const float* Wq    = (const float*)d_in[2];
    const float* bq    = (const float*)d_in[3];
    const float* Wk    = (const float*)d_in[4];
    const float* bk    = (const float*)d_in[5];
    const float* Wv    = (const float*)d_in[6];
    const float* bv    = (const float*)d_in[7];
    const float* alpha = (const float*)d_in[8];
    float* out = (float*)d_out;

    _Float16* qh = (_Float16*)d_ws;                     // [B][P1][32]
    _Float16* ql = qh + (size_t)B * P1 * CQ;
    _Float16* kh = ql + (size_t)B * P1 * CQ;            // [B][P2][32]
    _Float16* kl = kh + (size_t)B * P2 * CQ;
    _Float16* vh = kl + (size_t)B * P2 * CQ;            // [B][C][P1]
    _Float16* wqh = vh + (size_t)B * C * P1;            // [32][256]
    _Float16* wql = wqh + CQ * C;
    _Float16* wkh = wql + CQ * C;
    _Float16* wkl = wkh + CQ * C;
    _Float16* wvh = wkl + CQ * C;                       // [256][256]
    float*    li  = (float*)(wvh + C * C);              // [B][P1]

    prep_w<<<dim3(32), 256, 0, stream>>>(Wq, Wk, Wv, wqh, wql, wkh, wkl, wvh);
    prep1<<<dim3(B, P1 / 32), 256, 0, stream>>>(x1, wqh, wql, wvh, bq, bv, qh, ql, vh);
    prep2<<<dim3(B, P2 / 32), 256, 0, stream>>>(x2, wkh, wkl, bk, kh, kl);
    stats_l<<<dim3(B, P1 / 64), 512, 0, stream>>>(qh, ql, kh, kl, li);
    attn_gemm<<<dim3(512), 256, 0, stream>>>(qh, ql, kh, kl, vh, li, x2, alpha, out);
}